// Round 2
// baseline (639.078 us; speedup 1.0000x reference)
//
#include <hip/hip_runtime.h>
#include <hip/hip_bf16.h>

#define NT 256

__device__ __forceinline__ float b2f(unsigned short u) {
  return __uint_as_float(((unsigned int)u) << 16);
}
__device__ __forceinline__ unsigned short f2b(float f) {
  unsigned int x = __float_as_uint(f);
  return (unsigned short)((x + 0x7fffu + ((x >> 16) & 1u)) >> 16);
}
__device__ __forceinline__ float sigmoidf(float x) {
  return __builtin_amdgcn_rcpf(1.0f + __expf(-x));
}

// ---------------- dtype detect ----------------
// Samples even-index ushorts of the keys buffer. In fp32 mode these are
// mantissa halves (uniform bits -> huge exponents common); in bf16 mode they
// are N(0,1) values (|v| < 2^17 always). flag: 1 = fp32 inputs, 0 = bf16.
__global__ void detect_dtype(const unsigned short* __restrict__ keys_u,
                             unsigned long long n_ushort_min,
                             int* __restrict__ flag) {
  __shared__ int anybig;
  if (threadIdx.x == 0) anybig = 0;
  __syncthreads();
  unsigned long long stride = (n_ushort_min / 4096ull) & ~1ull;
  if (stride == 0) stride = 2;
  int big = 0;
  for (int i = threadIdx.x; i < 4096; i += NT) {
    unsigned long long idx = (unsigned long long)i * stride;
    if (idx < n_ushort_min) {
      unsigned short u = keys_u[idx];
      int e = (u >> 7) & 0xFF;
      if (e >= 0x90) big = 1;  // |bf16| >= 2^17: impossible for real data
    }
  }
  if (big) atomicOr(&anybig, 1);
  __syncthreads();
  if (threadIdx.x == 0) flag[0] = anybig;
}

// ================= FP32-input path (flag==1) =================
// B=4096, T=200, E=64, D=256, H0=80, H1=40. One block per batch row.
// 256 threads = 64 t-lanes x 4 h-groups. Keys staged to LDS as bf16.
__global__ __launch_bounds__(NT, 2) void din_attn_f32(
    const float* __restrict__ q,
    const float* __restrict__ keys,
    const int* __restrict__ klen,
    const float* __restrict__ W0,
    const float* __restrict__ b0,
    const float* __restrict__ W1,
    const float* __restrict__ b1,
    const float* __restrict__ W2,
    const float* __restrict__ b2,
    float* __restrict__ out,
    const int* __restrict__ flag)
{
  if (flag[0] != 1) return;
  const int b = blockIdx.x;
  const int tid = threadIdx.x;

  __shared__ __align__(16) float qf[64];
  __shared__ __align__(16) unsigned short klds[200 * 72];  // 144B row pitch
  __shared__ __align__(16) float Wb[64 * 80];              // folded layer-1 weight
  __shared__ __align__(16) float cf[80];                   // folded layer-1 bias
  __shared__ __align__(16) float W1f[80 * 48];             // padded 40->48
  __shared__ __align__(16) float b1f[48];
  __shared__ __align__(16) float w2f[48];
  __shared__ __align__(16) unsigned short h0lds[64 * 80];
  __shared__ __align__(16) float score[256];
  __shared__ __align__(16) float part[256];
  __shared__ float b2v;

  int L = klen[b];
  L = max(0, min(200, L));

  if (tid < 64) qf[tid] = q[b * 64 + tid];
  if (tid == 0) b2v = b2[0];
  __syncthreads();

  // ---- stage keys rows [0,L): fp32 global -> bf16 LDS, coalesced 16B loads ----
  {
    const float4* src = (const float4*)(keys + (size_t)b * 12800);
    const int nch = L * 16;  // 16x (4-float) chunks per 64-float row
    for (int idx = tid; idx < nch; idx += NT) {
      const int row = idx >> 4, c = idx & 15;
      float4 v = src[row * 16 + c];
      ushort4 o;
      o.x = f2b(v.x); o.y = f2b(v.y); o.z = f2b(v.z); o.w = f2b(v.w);
      *(ushort4*)&klds[row * 72 + c * 4] = o;
    }
  }
  // ---- Wb[e][h] = W0b - W0c + q[e]*W0d ----
  for (int idx = tid; idx < 5120; idx += NT) {
    const int e = idx / 80, h = idx - e * 80;
    Wb[idx] = W0[(64 + e) * 80 + h] - W0[(128 + e) * 80 + h]
              + qf[e] * W0[(192 + e) * 80 + h];
  }
  // ---- cf[h] = b0[h] + sum_e q[e]*(W0a+W0c)[e][h] ----
  if (tid < 80) {
    float acc = b0[tid];
    #pragma unroll 8
    for (int e = 0; e < 64; ++e)
      acc += qf[e] * (W0[e * 80 + tid] + W0[(128 + e) * 80 + tid]);
    cf[tid] = acc;
  }
  // ---- W1 padded to 48 cols ----
  for (int idx = tid; idx < 80 * 48; idx += NT) {
    const int h = idx / 48, j = idx - h * 48;
    W1f[idx] = (j < 40) ? W1[h * 40 + j] : 0.0f;
  }
  if (tid < 48) {
    b1f[tid] = (tid < 40) ? b1[tid] : 0.0f;
    w2f[tid] = (tid < 40) ? W2[tid] : 0.0f;
  }
  score[tid] = 0.0f;
  __syncthreads();

  const int tloc = tid >> 2;  // 0..63 : which t
  const int hg = tid & 3;     // 0..3  : hidden-unit slice
  const int passes = (L + 63) >> 6;

  for (int p = 0; p < passes; ++p) {
    const int t = (p << 6) + tloc;
    const bool act = (t < L);

    if (act) {
      uint4 kraw[8];
      const uint4* kp = (const uint4*)&klds[t * 72];
      #pragma unroll
      for (int i = 0; i < 8; ++i) kraw[i] = kp[i];

      float acc[20];
      #pragma unroll
      for (int ii = 0; ii < 5; ++ii) {
        const float4 c4 = *(const float4*)&cf[hg * 20 + ii * 4];
        acc[ii*4+0] = c4.x; acc[ii*4+1] = c4.y; acc[ii*4+2] = c4.z; acc[ii*4+3] = c4.w;
      }
      const float* wbase = &Wb[hg * 20];
      #pragma unroll 2
      for (int i = 0; i < 8; ++i) {
        const uint4 r = kraw[i];
        const unsigned int rv[4] = {r.x, r.y, r.z, r.w};
        #pragma unroll
        for (int jj = 0; jj < 4; ++jj) {
          const float k0 = __uint_as_float(rv[jj] << 16);
          const float k1 = __uint_as_float(rv[jj] & 0xffff0000u);
          const float* w0p = wbase + (i * 8 + jj * 2) * 80;
          #pragma unroll
          for (int ii = 0; ii < 5; ++ii) {
            const float4 w = *(const float4*)(w0p + ii * 4);
            acc[ii*4+0] += k0 * w.x; acc[ii*4+1] += k0 * w.y;
            acc[ii*4+2] += k0 * w.z; acc[ii*4+3] += k0 * w.w;
          }
          #pragma unroll
          for (int ii = 0; ii < 5; ++ii) {
            const float4 w = *(const float4*)(w0p + 80 + ii * 4);
            acc[ii*4+0] += k1 * w.x; acc[ii*4+1] += k1 * w.y;
            acc[ii*4+2] += k1 * w.z; acc[ii*4+3] += k1 * w.w;
          }
        }
      }
      #pragma unroll
      for (int i = 0; i < 20; ++i)
        h0lds[tloc * 80 + hg * 20 + i] = f2b(sigmoidf(acc[i]));
    }
    __syncthreads();

    if (act) {
      float h1[12];
      #pragma unroll
      for (int ii = 0; ii < 3; ++ii) {
        const float4 b4 = *(const float4*)&b1f[hg * 12 + ii * 4];
        h1[ii*4+0] = b4.x; h1[ii*4+1] = b4.y; h1[ii*4+2] = b4.z; h1[ii*4+3] = b4.w;
      }
      uint4 h0raw[10];
      const uint4* hp = (const uint4*)&h0lds[tloc * 80];
      #pragma unroll
      for (int i = 0; i < 10; ++i) h0raw[i] = hp[i];
      #pragma unroll 2
      for (int i = 0; i < 10; ++i) {
        const uint4 r = h0raw[i];
        const unsigned int rv[4] = {r.x, r.y, r.z, r.w};
        #pragma unroll
        for (int jj = 0; jj < 4; ++jj) {
          const float v0 = __uint_as_float(rv[jj] << 16);
          const float v1 = __uint_as_float(rv[jj] & 0xffff0000u);
          const int h = i * 8 + jj * 2;
          const float* wp0 = &W1f[h * 48 + hg * 12];
          #pragma unroll
          for (int ii = 0; ii < 3; ++ii) {
            const float4 w = *(const float4*)(wp0 + ii * 4);
            h1[ii*4+0] += v0 * w.x; h1[ii*4+1] += v0 * w.y;
            h1[ii*4+2] += v0 * w.z; h1[ii*4+3] += v0 * w.w;
          }
          #pragma unroll
          for (int ii = 0; ii < 3; ++ii) {
            const float4 w = *(const float4*)(wp0 + 48 + ii * 4);
            h1[ii*4+0] += v1 * w.x; h1[ii*4+1] += v1 * w.y;
            h1[ii*4+2] += v1 * w.z; h1[ii*4+3] += v1 * w.w;
          }
        }
      }
      float pd = 0.0f;
      #pragma unroll
      for (int i = 0; i < 12; ++i)
        pd += sigmoidf(h1[i]) * w2f[hg * 12 + i];
      pd += __shfl_xor(pd, 1);
      pd += __shfl_xor(pd, 2);
      score[t] = sigmoidf(pd + b2v);
    }
    __syncthreads();
  }

  // ---- weighted sum: out[e] = sum_{t<L} score[t] * keys[t][e] ----
  {
    const int e = tid & 63, stripe = tid >> 6;
    float acc = 0.0f;
    for (int t = stripe; t < L; t += 4)
      acc += score[t] * b2f(klds[t * 72 + e]);
    part[tid] = acc;
  }
  __syncthreads();
  if (tid < 64) {
    const float r = part[tid] + part[64 + tid] + part[128 + tid] + part[192 + tid];
    out[b * 64 + tid] = r;
  }
}

// ================= BF16-input path (flag==0) =================
__global__ __launch_bounds__(NT, 2) void din_attn_bf16(
    const unsigned short* __restrict__ q,
    const unsigned short* __restrict__ keys,
    const int* __restrict__ klen,
    const unsigned short* __restrict__ W0,
    const unsigned short* __restrict__ b0,
    const unsigned short* __restrict__ W1,
    const unsigned short* __restrict__ b1,
    const unsigned short* __restrict__ W2,
    const unsigned short* __restrict__ b2,
    unsigned short* __restrict__ out,
    const int* __restrict__ flag)
{
  if (flag[0] != 0) return;
  const int b = blockIdx.x;
  const int tid = threadIdx.x;

  __shared__ __align__(16) float qf[64];
  __shared__ __align__(16) unsigned short klds[200 * 72];
  __shared__ __align__(16) float Wb[64 * 80];
  __shared__ __align__(16) float cf[80];
  __shared__ __align__(16) float W1f[80 * 48];
  __shared__ __align__(16) float b1f[48];
  __shared__ __align__(16) float w2f[48];
  __shared__ __align__(16) unsigned short h0lds[64 * 80];
  __shared__ __align__(16) float score[256];
  __shared__ __align__(16) float part[256];
  __shared__ float b2v;

  int L = klen[b];
  L = max(0, min(200, L));

  if (tid < 64) qf[tid] = b2f(q[b * 64 + tid]);
  if (tid == 0) b2v = b2f(b2[0]);
  __syncthreads();

  {
    const uint4* src = (const uint4*)(keys + (size_t)b * 12800);
    const int nch = L * 8;
    for (int idx = tid; idx < nch; idx += NT) {
      const int row = idx >> 3, c = idx & 7;
      uint4 v = src[row * 8 + c];
      *(uint4*)&klds[row * 72 + c * 8] = v;
    }
  }
  for (int idx = tid; idx < 5120; idx += NT) {
    const int e = idx / 80, h = idx - e * 80;
    Wb[idx] = b2f(W0[(64 + e) * 80 + h]) - b2f(W0[(128 + e) * 80 + h])
              + qf[e] * b2f(W0[(192 + e) * 80 + h]);
  }
  if (tid < 80) {
    float acc = b2f(b0[tid]);
    #pragma unroll 8
    for (int e = 0; e < 64; ++e)
      acc += qf[e] * (b2f(W0[e * 80 + tid]) + b2f(W0[(128 + e) * 80 + tid]));
    cf[tid] = acc;
  }
  for (int idx = tid; idx < 80 * 48; idx += NT) {
    const int h = idx / 48, j = idx - h * 48;
    W1f[idx] = (j < 40) ? b2f(W1[h * 40 + j]) : 0.0f;
  }
  if (tid < 48) {
    b1f[tid] = (tid < 40) ? b2f(b1[tid]) : 0.0f;
    w2f[tid] = (tid < 40) ? b2f(W2[tid]) : 0.0f;
  }
  score[tid] = 0.0f;
  __syncthreads();

  const int tloc = tid >> 2;
  const int hg = tid & 3;
  const int passes = (L + 63) >> 6;

  for (int p = 0; p < passes; ++p) {
    const int t = (p << 6) + tloc;
    const bool act = (t < L);

    if (act) {
      uint4 kraw[8];
      const uint4* kp = (const uint4*)&klds[t * 72];
      #pragma unroll
      for (int i = 0; i < 8; ++i) kraw[i] = kp[i];

      float acc[20];
      #pragma unroll
      for (int ii = 0; ii < 5; ++ii) {
        const float4 c4 = *(const float4*)&cf[hg * 20 + ii * 4];
        acc[ii*4+0] = c4.x; acc[ii*4+1] = c4.y; acc[ii*4+2] = c4.z; acc[ii*4+3] = c4.w;
      }
      const float* wbase = &Wb[hg * 20];
      #pragma unroll 2
      for (int i = 0; i < 8; ++i) {
        const uint4 r = kraw[i];
        const unsigned int rv[4] = {r.x, r.y, r.z, r.w};
        #pragma unroll
        for (int jj = 0; jj < 4; ++jj) {
          const float k0 = __uint_as_float(rv[jj] << 16);
          const float k1 = __uint_as_float(rv[jj] & 0xffff0000u);
          const float* w0p = wbase + (i * 8 + jj * 2) * 80;
          #pragma unroll
          for (int ii = 0; ii < 5; ++ii) {
            const float4 w = *(const float4*)(w0p + ii * 4);
            acc[ii*4+0] += k0 * w.x; acc[ii*4+1] += k0 * w.y;
            acc[ii*4+2] += k0 * w.z; acc[ii*4+3] += k0 * w.w;
          }
          #pragma unroll
          for (int ii = 0; ii < 5; ++ii) {
            const float4 w = *(const float4*)(w0p + 80 + ii * 4);
            acc[ii*4+0] += k1 * w.x; acc[ii*4+1] += k1 * w.y;
            acc[ii*4+2] += k1 * w.z; acc[ii*4+3] += k1 * w.w;
          }
        }
      }
      #pragma unroll
      for (int i = 0; i < 20; ++i)
        h0lds[tloc * 80 + hg * 20 + i] = f2b(sigmoidf(acc[i]));
    }
    __syncthreads();

    if (act) {
      float h1[12];
      #pragma unroll
      for (int ii = 0; ii < 3; ++ii) {
        const float4 b4 = *(const float4*)&b1f[hg * 12 + ii * 4];
        h1[ii*4+0] = b4.x; h1[ii*4+1] = b4.y; h1[ii*4+2] = b4.z; h1[ii*4+3] = b4.w;
      }
      uint4 h0raw[10];
      const uint4* hp = (const uint4*)&h0lds[tloc * 80];
      #pragma unroll
      for (int i = 0; i < 10; ++i) h0raw[i] = hp[i];
      #pragma unroll 2
      for (int i = 0; i < 10; ++i) {
        const uint4 r = h0raw[i];
        const unsigned int rv[4] = {r.x, r.y, r.z, r.w};
        #pragma unroll
        for (int jj = 0; jj < 4; ++jj) {
          const float v0 = __uint_as_float(rv[jj] << 16);
          const float v1 = __uint_as_float(rv[jj] & 0xffff0000u);
          const int h = i * 8 + jj * 2;
          const float* wp0 = &W1f[h * 48 + hg * 12];
          #pragma unroll
          for (int ii = 0; ii < 3; ++ii) {
            const float4 w = *(const float4*)(wp0 + ii * 4);
            h1[ii*4+0] += v0 * w.x; h1[ii*4+1] += v0 * w.y;
            h1[ii*4+2] += v0 * w.z; h1[ii*4+3] += v0 * w.w;
          }
          #pragma unroll
          for (int ii = 0; ii < 3; ++ii) {
            const float4 w = *(const float4*)(wp0 + 48 + ii * 4);
            h1[ii*4+0] += v1 * w.x; h1[ii*4+1] += v1 * w.y;
            h1[ii*4+2] += v1 * w.z; h1[ii*4+3] += v1 * w.w;
          }
        }
      }
      float pd = 0.0f;
      #pragma unroll
      for (int i = 0; i < 12; ++i)
        pd += sigmoidf(h1[i]) * w2f[hg * 12 + i];
      pd += __shfl_xor(pd, 1);
      pd += __shfl_xor(pd, 2);
      score[t] = sigmoidf(pd + b2v);
    }
    __syncthreads();
  }

  {
    const int e = tid & 63, stripe = tid >> 6;
    float acc = 0.0f;
    for (int t = stripe; t < L; t += 4)
      acc += score[t] * b2f(klds[t * 72 + e]);
    part[tid] = acc;
  }
  __syncthreads();
  if (tid < 64) {
    const float r = part[tid] + part[64 + tid] + part[128 + tid] + part[192 + tid];
    out[b * 64 + tid] = f2b(r);
  }
}

extern "C" void kernel_launch(void* const* d_in, const int* in_sizes, int n_in,
                              void* d_out, int out_size, void* d_ws, size_t ws_size,
                              hipStream_t stream) {
  const int B = in_sizes[2];  // keys_length: one entry per batch row
  int* flag = (int*)d_ws;
  // keys element count (bf16-interpretation lower bound on ushort count)
  unsigned long long nk = (unsigned long long)in_sizes[1];
  detect_dtype<<<1, NT, 0, stream>>>((const unsigned short*)d_in[1], nk, flag);
  din_attn_f32<<<B, NT, 0, stream>>>(
      (const float*)d_in[0], (const float*)d_in[1], (const int*)d_in[2],
      (const float*)d_in[3], (const float*)d_in[4], (const float*)d_in[5],
      (const float*)d_in[6], (const float*)d_in[7], (const float*)d_in[8],
      (float*)d_out, flag);
  din_attn_bf16<<<B, NT, 0, stream>>>(
      (const unsigned short*)d_in[0], (const unsigned short*)d_in[1],
      (const int*)d_in[2], (const unsigned short*)d_in[3],
      (const unsigned short*)d_in[4], (const unsigned short*)d_in[5],
      (const unsigned short*)d_in[6], (const unsigned short*)d_in[7],
      (const unsigned short*)d_in[8], (unsigned short*)d_out, flag);
}

// Round 3
// 587.582 us; speedup vs baseline: 1.0876x; 1.0876x over previous
//
#include <hip/hip_runtime.h>
#include <hip/hip_bf16.h>

#define NT 256

__device__ __forceinline__ float b2f(unsigned short u) {
  return __uint_as_float(((unsigned int)u) << 16);
}
__device__ __forceinline__ unsigned short f2b(float f) {
  unsigned int x = __float_as_uint(f);
  return (unsigned short)((x + 0x7fffu + ((x >> 16) & 1u)) >> 16);
}
__device__ __forceinline__ float sigmoidf(float x) {
  return __builtin_amdgcn_rcpf(1.0f + __expf(-x));
}

// ---- precompute C[b][h] = b0[h] + sum_e q[b][e] * (W0a + W0c)[e][h] ----
// grid = ceil(B/32), 32 batch rows per block.
__global__ __launch_bounds__(NT, 2) void prep_c(
    const float* __restrict__ q, const float* __restrict__ W0,
    const float* __restrict__ b0, float* __restrict__ C, int B)
{
  __shared__ float Wac[64 * 80];
  __shared__ float qlds[32 * 64];
  const int bbase = blockIdx.x * 32, tid = threadIdx.x;
  for (int idx = tid; idx < 5120; idx += NT) {
    const int e = idx / 80, h = idx - e * 80;
    Wac[idx] = W0[e * 80 + h] + W0[(128 + e) * 80 + h];
  }
  for (int idx = tid; idx < 2048; idx += NT) {
    const int bl = idx >> 6, e = idx & 63;
    const int bg = bbase + bl;
    qlds[idx] = (bg < B) ? q[bg * 64 + e] : 0.0f;
  }
  __syncthreads();
  #pragma unroll
  for (int i = 0; i < 10; ++i) {
    const int idx = tid + i * NT;  // < 2560 = 32*80
    const int bl = idx / 80, h = idx - bl * 80;
    const int bg = bbase + bl;
    if (bg < B) {
      float acc = b0[h];
      #pragma unroll 8
      for (int e = 0; e < 64; ++e) acc += qlds[bl * 64 + e] * Wac[e * 80 + h];
      C[bg * 80 + h] = acc;
    }
  }
}

// ---- main: one block per batch row; per-pass key staging + fused epilogue ----
// B=4096, T=200, E=64, H0=80, H1=40. 256 thr = 64 t-lanes x 4 h-groups.
// LDS ~53.6 KB -> 3 blocks/CU.
__global__ __launch_bounds__(NT, 3) void din_attn_main(
    const float* __restrict__ q,
    const float* __restrict__ keys,
    const int* __restrict__ klen,
    const float* __restrict__ W0,
    const float* __restrict__ b0,
    const float* __restrict__ W1,
    const float* __restrict__ b1,
    const float* __restrict__ W2,
    const float* __restrict__ b2,
    float* __restrict__ out,
    const float* __restrict__ Cpre)
{
  const int b = blockIdx.x;
  const int tid = threadIdx.x;

  __shared__ __align__(16) unsigned short kbuf[64 * 72];  // 9216 B, 144B pitch
  __shared__ __align__(16) float Wb[64 * 80];             // 20480 B (aliased as part[] at end)
  __shared__ __align__(16) float cf[80];
  __shared__ __align__(16) float W1f[80 * 40];            // 12800 B
  __shared__ __align__(16) float b1f[40];
  __shared__ __align__(16) float w2f[40];
  __shared__ __align__(16) unsigned short h0lds[64 * 80]; // 10240 B
  __shared__ __align__(16) float score_qf[64];            // qf in setup, score in loop
  __shared__ float b2v;

  int L = klen[b];
  L = max(0, min(200, L));

  if (tid < 64) score_qf[tid] = q[b * 64 + tid];
  if (tid == 0) b2v = b2[0];
  __syncthreads();

  // ---- fold layer-1 weight: Wb[e][h] = W0b - W0c + q[e]*W0d ----
  for (int idx = tid; idx < 5120; idx += NT) {
    const int e = idx / 80, h = idx - e * 80;
    Wb[idx] = W0[(64 + e) * 80 + h] - W0[(128 + e) * 80 + h]
              + score_qf[e] * W0[(192 + e) * 80 + h];
  }
  // ---- folded bias: precomputed (fast) or inline (fallback) ----
  if (Cpre != nullptr) {
    if (tid < 80) cf[tid] = Cpre[b * 80 + tid];
  } else if (tid < 80) {
    float acc = b0[tid];
    #pragma unroll 8
    for (int e = 0; e < 64; ++e)
      acc += score_qf[e] * (W0[e * 80 + tid] + W0[(128 + e) * 80 + tid]);
    cf[tid] = acc;
  }
  // ---- W1 / biases to LDS ----
  for (int idx = tid; idx < 3200; idx += NT) W1f[idx] = W1[idx];
  if (tid < 40) { b1f[tid] = b1[tid]; w2f[tid] = W2[tid]; }
  __syncthreads();

  const int tloc = tid >> 2;      // 0..63 : row within pass
  const int hg = tid & 3;         // 0..3  : hidden-unit slice
  const int e_ep = tid & 63;      // epilogue: which feature
  const int stripe = tid >> 6;    // epilogue: row stripe
  float wacc = 0.0f;
  const int passes = (L + 63) >> 6;

  for (int p = 0; p < passes; ++p) {
    const int nr = min(64, L - (p << 6));
    // ---- stage this pass's key rows: fp32 global -> bf16 LDS ----
    {
      const float4* src = (const float4*)(keys + (size_t)b * 12800 + ((size_t)p << 12));
      const int nch = nr * 16;
      for (int idx = tid; idx < nch; idx += NT) {
        const int row = idx >> 4, c = idx & 15;
        float4 v = src[row * 16 + c];
        ushort4 o;
        o.x = f2b(v.x); o.y = f2b(v.y); o.z = f2b(v.z); o.w = f2b(v.w);
        *(ushort4*)&kbuf[row * 72 + c * 4] = o;
      }
    }
    __syncthreads();

    const bool act = (tloc < nr);
    if (act) {
      // ---- layer 1: h0[hg*20 .. +19] for row tloc ----
      uint4 kraw[8];
      const uint4* kp = (const uint4*)&kbuf[tloc * 72];
      #pragma unroll
      for (int i = 0; i < 8; ++i) kraw[i] = kp[i];

      float acc[20];
      #pragma unroll
      for (int ii = 0; ii < 5; ++ii) {
        const float4 c4 = *(const float4*)&cf[hg * 20 + ii * 4];
        acc[ii*4+0] = c4.x; acc[ii*4+1] = c4.y; acc[ii*4+2] = c4.z; acc[ii*4+3] = c4.w;
      }
      const float* wbase = &Wb[hg * 20];
      #pragma unroll 2
      for (int i = 0; i < 8; ++i) {
        const uint4 r = kraw[i];
        const unsigned int rv[4] = {r.x, r.y, r.z, r.w};
        #pragma unroll
        for (int jj = 0; jj < 4; ++jj) {
          const float k0 = __uint_as_float(rv[jj] << 16);
          const float k1 = __uint_as_float(rv[jj] & 0xffff0000u);
          const float* w0p = wbase + (i * 8 + jj * 2) * 80;
          #pragma unroll
          for (int ii = 0; ii < 5; ++ii) {
            const float4 w = *(const float4*)(w0p + ii * 4);
            acc[ii*4+0] += k0 * w.x; acc[ii*4+1] += k0 * w.y;
            acc[ii*4+2] += k0 * w.z; acc[ii*4+3] += k0 * w.w;
          }
          #pragma unroll
          for (int ii = 0; ii < 5; ++ii) {
            const float4 w = *(const float4*)(w0p + 80 + ii * 4);
            acc[ii*4+0] += k1 * w.x; acc[ii*4+1] += k1 * w.y;
            acc[ii*4+2] += k1 * w.z; acc[ii*4+3] += k1 * w.w;
          }
        }
      }
      #pragma unroll
      for (int i = 0; i < 20; ++i)
        h0lds[tloc * 80 + hg * 20 + i] = f2b(sigmoidf(acc[i]));
    }
    __syncthreads();

    if (act) {
      // ---- layer 2: h1[hg*10 .. +9]; layer 3 partial dot ----
      float h1[10];
      {
        const float2* bp = (const float2*)&b1f[hg * 10];
        #pragma unroll
        for (int m = 0; m < 5; ++m) { h1[2*m] = bp[m].x; h1[2*m+1] = bp[m].y; }
      }
      uint4 h0raw[10];
      const uint4* hp = (const uint4*)&h0lds[tloc * 80];
      #pragma unroll
      for (int i = 0; i < 10; ++i) h0raw[i] = hp[i];
      #pragma unroll 2
      for (int i = 0; i < 10; ++i) {
        const uint4 r = h0raw[i];
        const unsigned int rv[4] = {r.x, r.y, r.z, r.w};
        #pragma unroll
        for (int jj = 0; jj < 4; ++jj) {
          const float v0 = __uint_as_float(rv[jj] << 16);
          const float v1 = __uint_as_float(rv[jj] & 0xffff0000u);
          const int h = i * 8 + jj * 2;
          const float2* wp0 = (const float2*)&W1f[h * 40 + hg * 10];
          const float2* wp1 = (const float2*)&W1f[(h + 1) * 40 + hg * 10];
          #pragma unroll
          for (int m = 0; m < 5; ++m) {
            const float2 w = wp0[m];
            h1[2*m] += v0 * w.x; h1[2*m+1] += v0 * w.y;
          }
          #pragma unroll
          for (int m = 0; m < 5; ++m) {
            const float2 w = wp1[m];
            h1[2*m] += v1 * w.x; h1[2*m+1] += v1 * w.y;
          }
        }
      }
      float pd = 0.0f;
      #pragma unroll
      for (int i = 0; i < 10; ++i)
        pd += sigmoidf(h1[i]) * w2f[hg * 10 + i];
      pd += __shfl_xor(pd, 1);
      pd += __shfl_xor(pd, 2);
      score_qf[tloc] = sigmoidf(pd + b2v);  // all 4 hg lanes write same value
    }
    __syncthreads();

    // ---- fused epilogue: accumulate this pass's weighted sum ----
    #pragma unroll 4
    for (int i = 0; i < 16; ++i) {
      const int t = stripe + 4 * i;
      if (t < nr) wacc += score_qf[t] * b2f(kbuf[t * 72 + e_ep]);
    }
    __syncthreads();  // protect kbuf/score before next pass overwrites
  }

  // ---- final reduce: part aliases Wb (dead after last layer-1 + sync) ----
  float* part = (float*)Wb;
  part[tid] = wacc;
  __syncthreads();
  if (tid < 64) {
    out[b * 64 + tid] =
        part[tid] + part[64 + tid] + part[128 + tid] + part[192 + tid];
  }
}

extern "C" void kernel_launch(void* const* d_in, const int* in_sizes, int n_in,
                              void* d_out, int out_size, void* d_ws, size_t ws_size,
                              hipStream_t stream) {
  const int B = in_sizes[2];  // keys_length: one entry per batch row
  const float* Cpre = nullptr;
  if (ws_size >= (size_t)B * 80 * sizeof(float)) {
    float* C = (float*)d_ws;
    prep_c<<<(B + 31) / 32, NT, 0, stream>>>(
        (const float*)d_in[0], (const float*)d_in[3], (const float*)d_in[4], C, B);
    Cpre = C;
  }
  din_attn_main<<<B, NT, 0, stream>>>(
      (const float*)d_in[0], (const float*)d_in[1], (const int*)d_in[2],
      (const float*)d_in[3], (const float*)d_in[4], (const float*)d_in[5],
      (const float*)d_in[6], (const float*)d_in[7], (const float*)d_in[8],
      (float*)d_out, Cpre);
}

// Round 4
// 521.302 us; speedup vs baseline: 1.2259x; 1.1271x over previous
//
#include <hip/hip_runtime.h>
#include <hip/hip_bf16.h>

#define NT 256

__device__ __forceinline__ float b2f(unsigned short u) {
  return __uint_as_float(((unsigned int)u) << 16);
}
__device__ __forceinline__ unsigned short f2b(float f) {
  unsigned int x = __float_as_uint(f);
  return (unsigned short)((x + 0x7fffu + ((x >> 16) & 1u)) >> 16);
}
__device__ __forceinline__ float sigmoidf(float x) {
  return __builtin_amdgcn_rcpf(1.0f + __expf(-x));
}

// ---- precompute C[b][h] = b0[h] + sum_e q[b][e] * (W0a + W0c)[e][h] ----
__global__ __launch_bounds__(NT, 2) void prep_c(
    const float* __restrict__ q, const float* __restrict__ W0,
    const float* __restrict__ b0, float* __restrict__ C, int B)
{
  __shared__ float Wac[64 * 80];
  __shared__ float qlds[32 * 64];
  const int bbase = blockIdx.x * 32, tid = threadIdx.x;
  for (int idx = tid; idx < 5120; idx += NT) {
    const int e = idx / 80, h = idx - e * 80;
    Wac[idx] = W0[e * 80 + h] + W0[(128 + e) * 80 + h];
  }
  for (int idx = tid; idx < 2048; idx += NT) {
    const int bl = idx >> 6, e = idx & 63;
    const int bg = bbase + bl;
    qlds[idx] = (bg < B) ? q[bg * 64 + e] : 0.0f;
  }
  __syncthreads();
  #pragma unroll
  for (int i = 0; i < 10; ++i) {
    const int idx = tid + i * NT;  // < 2560 = 32*80
    const int bl = idx / 80, h = idx - bl * 80;
    const int bg = bbase + bl;
    if (bg < B) {
      float acc = b0[h];
      #pragma unroll 8
      for (int e = 0; e < 64; ++e) acc += qlds[bl * 64 + e] * Wac[e * 80 + h];
      C[bg * 80 + h] = acc;
    }
  }
}

// ---- main: one block per batch row; per-pass key staging + fused epilogue ----
// B=4096, T=200, E=64, H0=80, H1=40. 256 thr = 64 t-lanes x 4 h-groups.
// LDS ~53.6 KB -> 3 blocks/CU. ALL inner loops fully unrolled: no local-array
// dynamic indexing (round-3's `#pragma unroll 2` put kraw/h0raw in scratch ->
// 360 MB of WRITE_SIZE spill traffic).
__global__ __launch_bounds__(NT, 3) void din_attn_main(
    const float* __restrict__ q,
    const float* __restrict__ keys,
    const int* __restrict__ klen,
    const float* __restrict__ W0,
    const float* __restrict__ b0,
    const float* __restrict__ W1,
    const float* __restrict__ b1,
    const float* __restrict__ W2,
    const float* __restrict__ b2,
    float* __restrict__ out,
    const float* __restrict__ Cpre)
{
  const int b = blockIdx.x;
  const int tid = threadIdx.x;

  __shared__ __align__(16) unsigned short kbuf[64 * 72];  // 9216 B, 144B pitch
  __shared__ __align__(16) float Wb[64 * 80];             // 20480 B (part[] alias at end)
  __shared__ __align__(16) float cf[80];
  __shared__ __align__(16) float W1f[80 * 40];            // 12800 B
  __shared__ __align__(16) float b1f[40];
  __shared__ __align__(16) float w2f[40];
  __shared__ __align__(16) unsigned short h0lds[64 * 80]; // 10240 B
  __shared__ __align__(16) float score_qf[64];
  __shared__ float b2v;

  int L = klen[b];
  L = max(0, min(200, L));

  if (tid < 64) score_qf[tid] = q[b * 64 + tid];
  if (tid == 0) b2v = b2[0];
  __syncthreads();

  for (int idx = tid; idx < 5120; idx += NT) {
    const int e = idx / 80, h = idx - e * 80;
    Wb[idx] = W0[(64 + e) * 80 + h] - W0[(128 + e) * 80 + h]
              + score_qf[e] * W0[(192 + e) * 80 + h];
  }
  if (Cpre != nullptr) {
    if (tid < 80) cf[tid] = Cpre[b * 80 + tid];
  } else if (tid < 80) {
    float acc = b0[tid];
    #pragma unroll 8
    for (int e = 0; e < 64; ++e)
      acc += score_qf[e] * (W0[e * 80 + tid] + W0[(128 + e) * 80 + tid]);
    cf[tid] = acc;
  }
  for (int idx = tid; idx < 3200; idx += NT) W1f[idx] = W1[idx];
  if (tid < 40) { b1f[tid] = b1[tid]; w2f[tid] = W2[tid]; }
  __syncthreads();

  const int tloc = tid >> 2;      // 0..63 : row within pass
  const int hg = tid & 3;         // 0..3  : hidden-unit slice
  const int e_ep = tid & 63;      // epilogue: feature
  const int stripe = tid >> 6;    // epilogue: row stripe
  float wacc = 0.0f;
  const int passes = (L + 63) >> 6;

  for (int p = 0; p < passes; ++p) {
    const int nr = min(64, L - (p << 6));
    // ---- stage this pass's key rows: fp32 global -> bf16 LDS ----
    {
      const float4* src = (const float4*)(keys + (size_t)b * 12800 + ((size_t)p << 12));
      const int nch = nr * 16;
      for (int idx = tid; idx < nch; idx += NT) {
        const int row = idx >> 4, c = idx & 15;
        float4 v = src[row * 16 + c];
        ushort4 o;
        o.x = f2b(v.x); o.y = f2b(v.y); o.z = f2b(v.z); o.w = f2b(v.w);
        *(ushort4*)&kbuf[row * 72 + c * 4] = o;
      }
    }
    __syncthreads();

    const bool act = (tloc < nr);
    if (act) {
      // ---- layer 1: h0[hg*20 .. +19] for row tloc ----
      float acc[20];  // static indices only -> SROA to VGPRs
      #pragma unroll
      for (int ii = 0; ii < 5; ++ii) {
        const float4 c4 = *(const float4*)&cf[hg * 20 + ii * 4];
        acc[ii*4+0] = c4.x; acc[ii*4+1] = c4.y; acc[ii*4+2] = c4.z; acc[ii*4+3] = c4.w;
      }
      const uint4* kp = (const uint4*)&kbuf[tloc * 72];
      const float* wbase = &Wb[hg * 20];
      #pragma unroll
      for (int i = 0; i < 8; ++i) {          // FULL unroll: i static everywhere
        const uint4 r = kp[i];
        #pragma unroll
        for (int jj = 0; jj < 4; ++jj) {
          const unsigned int u = (jj == 0) ? r.x : (jj == 1) ? r.y : (jj == 2) ? r.z : r.w;
          const float k0 = __uint_as_float(u << 16);
          const float k1 = __uint_as_float(u & 0xffff0000u);
          const float* w0p = wbase + (i * 8 + jj * 2) * 80;
          #pragma unroll
          for (int ii = 0; ii < 5; ++ii) {
            const float4 w = *(const float4*)(w0p + ii * 4);
            acc[ii*4+0] += k0 * w.x; acc[ii*4+1] += k0 * w.y;
            acc[ii*4+2] += k0 * w.z; acc[ii*4+3] += k0 * w.w;
          }
          #pragma unroll
          for (int ii = 0; ii < 5; ++ii) {
            const float4 w = *(const float4*)(w0p + 80 + ii * 4);
            acc[ii*4+0] += k1 * w.x; acc[ii*4+1] += k1 * w.y;
            acc[ii*4+2] += k1 * w.z; acc[ii*4+3] += k1 * w.w;
          }
        }
      }
      #pragma unroll
      for (int i = 0; i < 20; ++i)
        h0lds[tloc * 80 + hg * 20 + i] = f2b(sigmoidf(acc[i]));
    }
    __syncthreads();

    if (act) {
      // ---- layer 2: h1[hg*10 .. +9]; layer 3 partial dot ----
      float h1[10];
      {
        const float2* bp = (const float2*)&b1f[hg * 10];
        #pragma unroll
        for (int m = 0; m < 5; ++m) { h1[2*m] = bp[m].x; h1[2*m+1] = bp[m].y; }
      }
      const uint4* hp = (const uint4*)&h0lds[tloc * 80];
      #pragma unroll
      for (int i = 0; i < 10; ++i) {         // FULL unroll
        const uint4 r = hp[i];
        #pragma unroll
        for (int jj = 0; jj < 4; ++jj) {
          const unsigned int u = (jj == 0) ? r.x : (jj == 1) ? r.y : (jj == 2) ? r.z : r.w;
          const float v0 = __uint_as_float(u << 16);
          const float v1 = __uint_as_float(u & 0xffff0000u);
          const int h = i * 8 + jj * 2;
          const float2* wp0 = (const float2*)&W1f[h * 40 + hg * 10];
          const float2* wp1 = (const float2*)&W1f[(h + 1) * 40 + hg * 10];
          #pragma unroll
          for (int m = 0; m < 5; ++m) {
            const float2 w = wp0[m];
            h1[2*m] += v0 * w.x; h1[2*m+1] += v0 * w.y;
          }
          #pragma unroll
          for (int m = 0; m < 5; ++m) {
            const float2 w = wp1[m];
            h1[2*m] += v1 * w.x; h1[2*m+1] += v1 * w.y;
          }
        }
      }
      float pd = 0.0f;
      #pragma unroll
      for (int i = 0; i < 10; ++i)
        pd += sigmoidf(h1[i]) * w2f[hg * 10 + i];
      pd += __shfl_xor(pd, 1);
      pd += __shfl_xor(pd, 2);
      score_qf[tloc] = sigmoidf(pd + b2v);
    }
    __syncthreads();

    // ---- fused epilogue: accumulate this pass's weighted sum ----
    #pragma unroll
    for (int i = 0; i < 16; ++i) {
      const int t = stripe + 4 * i;
      if (t < nr) wacc += score_qf[t] * b2f(kbuf[t * 72 + e_ep]);
    }
    __syncthreads();  // protect kbuf/score before next pass overwrites
  }

  float* part = (float*)Wb;  // Wb dead after last layer-1 use + sync
  part[tid] = wacc;
  __syncthreads();
  if (tid < 64) {
    out[b * 64 + tid] =
        part[tid] + part[64 + tid] + part[128 + tid] + part[192 + tid];
  }
}

extern "C" void kernel_launch(void* const* d_in, const int* in_sizes, int n_in,
                              void* d_out, int out_size, void* d_ws, size_t ws_size,
                              hipStream_t stream) {
  const int B = in_sizes[2];
  const float* Cpre = nullptr;
  if (ws_size >= (size_t)B * 80 * sizeof(float)) {
    float* C = (float*)d_ws;
    prep_c<<<(B + 31) / 32, NT, 0, stream>>>(
        (const float*)d_in[0], (const float*)d_in[3], (const float*)d_in[4], C, B);
    Cpre = C;
  }
  din_attn_main<<<B, NT, 0, stream>>>(
      (const float*)d_in[0], (const float*)d_in[1], (const int*)d_in[2],
      (const float*)d_in[3], (const float*)d_in[4], (const float*)d_in[5],
      (const float*)d_in[6], (const float*)d_in[7], (const float*)d_in[8],
      (float*)d_out, Cpre);
}

// Round 5
// 377.708 us; speedup vs baseline: 1.6920x; 1.3802x over previous
//
#include <hip/hip_runtime.h>
#include <hip/hip_bf16.h>

#define NT 256

typedef __attribute__((ext_vector_type(8))) short short8;   // 8 x bf16 (4 VGPRs)
typedef __attribute__((ext_vector_type(4))) float f32x4;    // MFMA accumulator

__device__ __forceinline__ float b2f(unsigned short u) {
  return __uint_as_float(((unsigned int)u) << 16);
}
__device__ __forceinline__ unsigned short f2b(float f) {
  unsigned int x = __float_as_uint(f);
  return (unsigned short)((x + 0x7fffu + ((x >> 16) & 1u)) >> 16);
}
__device__ __forceinline__ float sigmoidf(float x) {
  return __builtin_amdgcn_rcpf(1.0f + __expf(-x));
}

// ---- precompute C[b][h] = b0[h] + sum_e q[b][e] * (W0a + W0c)[e][h] ----
__global__ __launch_bounds__(NT, 2) void prep_c(
    const float* __restrict__ q, const float* __restrict__ W0,
    const float* __restrict__ b0, float* __restrict__ C, int B)
{
  __shared__ float Wac[64 * 80];
  __shared__ float qlds[32 * 64];
  const int bbase = blockIdx.x * 32, tid = threadIdx.x;
  for (int idx = tid; idx < 5120; idx += NT) {
    const int e = idx / 80, h = idx - e * 80;
    Wac[idx] = W0[e * 80 + h] + W0[(128 + e) * 80 + h];
  }
  for (int idx = tid; idx < 2048; idx += NT) {
    const int bl = idx >> 6, e = idx & 63;
    const int bg = bbase + bl;
    qlds[idx] = (bg < B) ? q[bg * 64 + e] : 0.0f;
  }
  __syncthreads();
  #pragma unroll
  for (int i = 0; i < 10; ++i) {
    const int idx = tid + i * NT;  // < 2560 = 32*80
    const int bl = idx / 80, h = idx - bl * 80;
    const int bg = bbase + bl;
    if (bg < B) {
      float acc = b0[h];
      #pragma unroll 8
      for (int e = 0; e < 64; ++e) acc += qlds[bl * 64 + e] * Wac[e * 80 + h];
      C[bg * 80 + h] = acc;
    }
  }
}

// ---- main: one block per batch row; MFMA layers 1+2 ----
// B=4096, T=200, E=64, H0=80, H1=40. 256 thr = 4 waves; wave w owns t-rows
// [16w,16w+16) of each 64-row pass. LDS ~46 KB -> 3 blocks/CU.
// Pitches: 16B-aligned rows, <=2-way bank aliasing (free per m136).
#define PK 72    // kbuf pitch (bf16 elems)
#define PW 72    // WbT pitch
#define PH 104   // h0 pitch (cols 0..79 live, 80..95 zero pad for K=96)
#define PW1 104  // W1T pitch
__global__ __launch_bounds__(NT, 3) void din_attn_main(
    const float* __restrict__ q,
    const float* __restrict__ keys,
    const int* __restrict__ klen,
    const float* __restrict__ W0,
    const float* __restrict__ b0,
    const float* __restrict__ W1,
    const float* __restrict__ b1,
    const float* __restrict__ W2,
    const float* __restrict__ b2,
    float* __restrict__ out,
    const float* __restrict__ Cpre)
{
  const int b = blockIdx.x;
  const int tid = threadIdx.x;

  __shared__ __align__(16) unsigned short kbuf[64 * PK];   //  9216 B
  __shared__ __align__(16) unsigned short WbT[80 * PW];    // 11520 B  [h][e]
  __shared__ __align__(16) unsigned short h0[64 * PH];     // 13312 B  [t][h]
  __shared__ __align__(16) unsigned short W1T[48 * PW1];   //  9984 B  [j][h]
  __shared__ __align__(16) float cf[80];
  __shared__ __align__(16) float b1f[48];
  __shared__ __align__(16) float w2f[48];
  __shared__ __align__(16) float qf[64];
  __shared__ __align__(16) float score[64];
  __shared__ __align__(16) float part[256];
  __shared__ float b2v;

  int L = klen[b];
  L = max(0, min(200, L));

  if (tid < 64) qf[tid] = q[b * 64 + tid];
  if (tid == 0) b2v = b2[0];
  __syncthreads();

  // ---- WbT[h][e] = bf16( W0b - W0c + q[e]*W0d ), coalesced W0 reads ----
  for (int idx = tid; idx < 5120; idx += NT) {
    const int e = idx / 80, h = idx - e * 80;
    const float v = W0[(64 + e) * 80 + h] - W0[(128 + e) * 80 + h]
                    + qf[e] * W0[(192 + e) * 80 + h];
    WbT[h * PW + e] = f2b(v);
  }
  // ---- folded bias ----
  if (Cpre != nullptr) {
    if (tid < 80) cf[tid] = Cpre[b * 80 + tid];
  } else if (tid < 80) {
    float acc = b0[tid];
    #pragma unroll 8
    for (int e = 0; e < 64; ++e)
      acc += qf[e] * (W0[e * 80 + tid] + W0[(128 + e) * 80 + tid]);
    cf[tid] = acc;
  }
  // ---- W1T[j][h] bf16, zero-padded (j>=40 or h>=80) ----
  for (int idx = tid; idx < 48 * PW1; idx += NT) {
    const int j = idx / PW1, h = idx - j * PW1;
    W1T[idx] = (j < 40 && h < 80) ? f2b(W1[h * 40 + j]) : (unsigned short)0;
  }
  // ---- zero kbuf (keep garbage rows finite) + h0 (incl. K-pad cols) ----
  for (int idx = tid; idx < (64 * PK) / 2; idx += NT) ((unsigned int*)kbuf)[idx] = 0u;
  for (int idx = tid; idx < (64 * PH) / 2; idx += NT) ((unsigned int*)h0)[idx] = 0u;
  if (tid < 48) {
    b1f[tid] = (tid < 40) ? b1[tid] : 0.0f;
    w2f[tid] = (tid < 40) ? W2[tid] : 0.0f;
  }
  __syncthreads();

  const int lane = tid & 63;
  const int wv = tid >> 6;        // wave id 0..3 -> m-tile
  const int lm = lane & 15;       // col-in-tile / A-row-in-tile
  const int quad = lane >> 4;     // k-group / D-row-group
  const int m = wv * 16 + lm;     // this lane's A-fragment row (t within pass)
  const int e_ep = tid & 63;      // epilogue: feature
  const int stripe = tid >> 6;    // epilogue: row stripe
  float wacc = 0.0f;
  const int passes = (L + 63) >> 6;

  for (int p = 0; p < passes; ++p) {
    const int nr = min(64, L - (p << 6));
    // ---- stage key rows: fp32 global -> bf16 LDS ----
    {
      const float4* src = (const float4*)(keys + (size_t)b * 12800 + ((size_t)p << 12));
      const int nch = nr * 16;
      for (int idx = tid; idx < nch; idx += NT) {
        const int row = idx >> 4, c = idx & 15;
        float4 v = src[row * 16 + c];
        ushort4 o;
        o.x = f2b(v.x); o.y = f2b(v.y); o.z = f2b(v.z); o.w = f2b(v.w);
        *(ushort4*)&kbuf[row * PK + c * 4] = o;
      }
    }
    __syncthreads();

    // ---- layer 1 (MFMA): h0[64x80] = sigmoid(kbuf[64x64] @ Wb[64x80] + cf) ----
    {
      const short8 a0 = *(const short8*)&kbuf[m * PK + quad * 8];        // k 0..31
      const short8 a1 = *(const short8*)&kbuf[m * PK + 32 + quad * 8];   // k 32..63
      #pragma unroll
      for (int nt = 0; nt < 5; ++nt) {
        const int col = nt * 16 + lm;
        const float cv = cf[col];
        f32x4 acc;
        acc[0] = cv; acc[1] = cv; acc[2] = cv; acc[3] = cv;
        const short8 w0f = *(const short8*)&WbT[col * PW + quad * 8];
        const short8 w1f = *(const short8*)&WbT[col * PW + 32 + quad * 8];
        acc = __builtin_amdgcn_mfma_f32_16x16x32_bf16(a0, w0f, acc, 0, 0, 0);
        acc = __builtin_amdgcn_mfma_f32_16x16x32_bf16(a1, w1f, acc, 0, 0, 0);
        // D: col=lane&15(+tile), row=quad*4+reg  -> sigmoid -> bf16 -> h0
        #pragma unroll
        for (int r = 0; r < 4; ++r)
          h0[(wv * 16 + quad * 4 + r) * PH + col] = f2b(sigmoidf(acc[r]));
      }
    }
    __syncthreads();  // h0 cross-lane visibility (conservative)

    // ---- layer 2 (MFMA) + layer 3: score = sigmoid(<sigmoid(h0@W1+b1), w2> + b2) ----
    {
      const short8 ha0 = *(const short8*)&h0[m * PH + quad * 8];         // k 0..31
      const short8 ha1 = *(const short8*)&h0[m * PH + 32 + quad * 8];    // k 32..63
      const short8 ha2 = *(const short8*)&h0[m * PH + 64 + quad * 8];    // k 64..95
      float pd[4] = {0.0f, 0.0f, 0.0f, 0.0f};
      #pragma unroll
      for (int nt = 0; nt < 3; ++nt) {
        const int col = nt * 16 + lm;     // h1-col 0..47 (40..47 padded)
        const float bv = b1f[col];
        f32x4 acc;
        acc[0] = bv; acc[1] = bv; acc[2] = bv; acc[3] = bv;
        const short8 wb0 = *(const short8*)&W1T[col * PW1 + quad * 8];
        const short8 wb1 = *(const short8*)&W1T[col * PW1 + 32 + quad * 8];
        const short8 wb2 = *(const short8*)&W1T[col * PW1 + 64 + quad * 8];
        acc = __builtin_amdgcn_mfma_f32_16x16x32_bf16(ha0, wb0, acc, 0, 0, 0);
        acc = __builtin_amdgcn_mfma_f32_16x16x32_bf16(ha1, wb1, acc, 0, 0, 0);
        acc = __builtin_amdgcn_mfma_f32_16x16x32_bf16(ha2, wb2, acc, 0, 0, 0);
        const float wj = w2f[col];        // 0 for padded cols
        #pragma unroll
        for (int r = 0; r < 4; ++r) pd[r] += sigmoidf(acc[r]) * wj;
      }
      // reduce over the 16 col-lanes (xor 1,2,4,8 stays within quad group)
      #pragma unroll
      for (int r = 0; r < 4; ++r) {
        pd[r] += __shfl_xor(pd[r], 1);
        pd[r] += __shfl_xor(pd[r], 2);
        pd[r] += __shfl_xor(pd[r], 4);
        pd[r] += __shfl_xor(pd[r], 8);
      }
      if (lm == 0) {
        #pragma unroll
        for (int r = 0; r < 4; ++r)
          score[wv * 16 + quad * 4 + r] = sigmoidf(pd[r] + b2v);
      }
    }
    __syncthreads();

    // ---- fused epilogue: wacc += score[t] * kbuf[t][e] over this pass ----
    #pragma unroll
    for (int i = 0; i < 16; ++i) {
      const int t = stripe + 4 * i;
      if (t < nr) wacc += score[t] * b2f(kbuf[t * PK + e_ep]);
    }
    __syncthreads();  // protect kbuf/score before next pass
  }

  part[tid] = wacc;
  __syncthreads();
  if (tid < 64) {
    out[b * 64 + tid] =
        part[tid] + part[64 + tid] + part[128 + tid] + part[192 + tid];
  }
}

extern "C" void kernel_launch(void* const* d_in, const int* in_sizes, int n_in,
                              void* d_out, int out_size, void* d_ws, size_t ws_size,
                              hipStream_t stream) {
  const int B = in_sizes[2];
  const float* Cpre = nullptr;
  if (ws_size >= (size_t)B * 80 * sizeof(float)) {
    float* C = (float*)d_ws;
    prep_c<<<(B + 31) / 32, NT, 0, stream>>>(
        (const float*)d_in[0], (const float*)d_in[3], (const float*)d_in[4], C, B);
    Cpre = C;
  }
  din_attn_main<<<B, NT, 0, stream>>>(
      (const float*)d_in[0], (const float*)d_in[1], (const int*)d_in[2],
      (const float*)d_in[3], (const float*)d_in[4], (const float*)d_in[5],
      (const float*)d_in[6], (const float*)d_in[7], (const float*)d_in[8],
      (float*)d_out, Cpre);
}